// Round 6
// baseline (3295.501 us; speedup 1.0000x reference)
//
#include <hip/hip_runtime.h>
#include <hip/hip_fp16.h>
#include <math.h>

#define B_ 64
#define T_ 512
#define F_ 128
#define H_ 512
#define NBLK 96
#define SPIN_MAX (1 << 18)

typedef _Float16 f16x8 __attribute__((ext_vector_type(8)));
typedef float f32x4 __attribute__((ext_vector_type(4)));
typedef int   i32x4 __attribute__((ext_vector_type(4)));

__device__ __forceinline__ unsigned short f2h(float f) {
    return __half_as_ushort(__float2half(f));   // RN
}
__device__ __forceinline__ float h2f(unsigned short u) {
    return __half2float(__ushort_as_half(u));
}

// ---------------------------------------------------------------------------
// One-time input transform: input[b][t][f] -> fp16 kquad stream
// xs[t][kp2=f>>2][b][{dw0,dw1}]; dw_p = fp16(4kp2+2p) | fp16(4kp2+2p+1)<<16.
// ---------------------------------------------------------------------------
__global__ void transpose_x(const float* __restrict__ in, unsigned* __restrict__ xs) {
    const int t = blockIdx.x;
    for (int idx = threadIdx.x; idx < B_ * F_ / 4; idx += blockDim.x) {
        const int kp2 = idx >> 6;       // 0..31
        const int bb = idx & 63;
        const float* src = in + (size_t)bb * T_ * F_ + (size_t)t * F_ + 4 * kp2;
        const unsigned h0 = f2h(src[0]), h1 = f2h(src[1]);
        const unsigned h2 = f2h(src[2]), h3 = f2h(src[3]);
        const unsigned dw0 = h0 | (h1 << 16);
        const unsigned dw1 = h2 | (h3 << 16);
        *(unsigned long long*)(xs + (size_t)t * 4096 + (size_t)kp2 * 128 + bb * 2) =
            ((unsigned long long)dw1 << 32) | dw0;
    }
}

// Fast device transcendentals (v_exp_f32 + v_rcp_f32, ~1e-7 rel err; fp16
// datapath quantization dominates). Proven R4.
__device__ __forceinline__ float sigmoid_(float x) {
    return __builtin_amdgcn_rcpf(1.0f + __expf(-x));
}
__device__ __forceinline__ float tanh_(float x) {
    return 1.0f - 2.0f * __builtin_amdgcn_rcpf(1.0f + __expf(2.0f * x));
}

// Device-coherent ops (relaxed agent-scope atomics -> sc1). Proven R0-R4.
__device__ __forceinline__ unsigned long long loadc_u64(const unsigned* p) {
    return __hip_atomic_load((const unsigned long long*)p, __ATOMIC_RELAXED,
                             __HIP_MEMORY_SCOPE_AGENT);
}
__device__ __forceinline__ unsigned loadc_u32(const unsigned* p) {
    return __hip_atomic_load(p, __ATOMIC_RELAXED, __HIP_MEMORY_SCOPE_AGENT);
}
__device__ __forceinline__ void storec_u64(unsigned* p, unsigned long long v) {
    __hip_atomic_store((unsigned long long*)p, v, __ATOMIC_RELAXED,
                       __HIP_MEMORY_SCOPE_AGENT);
}
__device__ __forceinline__ void storec_f(float* p, float v) {
    __hip_atomic_store(p, v, __ATOMIC_RELAXED, __HIP_MEMORY_SCOPE_AGENT);
}
__device__ __forceinline__ float loadc_f(const float* p) {
    return __hip_atomic_load(p, __ATOMIC_RELAXED, __HIP_MEMORY_SCOPE_AGENT);
}
__device__ __forceinline__ int loadc_i(const int* p) {
    return __hip_atomic_load(p, __ATOMIC_RELAXED, __HIP_MEMORY_SCOPE_AGENT);
}
__device__ __forceinline__ void storec_i(int* p, int v) {
    __hip_atomic_store(p, v, __ATOMIC_RELAXED, __HIP_MEMORY_SCOPE_AGENT);
}

// ---------------------------------------------------------------------------
// Wave-cooperative poll of 128 monotonic flags (stride 32 ints = 128 B):
// lane reads flags [lane] and [lane+64]; loop until __all >= need. Bounded.
// ---------------------------------------------------------------------------
__device__ __forceinline__ void poll128(const int* __restrict__ base, int need,
                                        int lane) {
    int g = 0;
    for (;;) {
        const bool ok = (loadc_i(base + lane * 32) >= need) &&
                        (loadc_i(base + (lane + 64) * 32) >= need);
        if (__all(ok)) return;
        if (++g >= SPIN_MAX) return;   // fail-fast: wrong answer, not hang
        __builtin_amdgcn_s_sleep(1);
    }
}

// ---------------------------------------------------------------------------
// Per-layer LSTM scan, flag-synchronized (no global barrier, no syncthreads
// in the loop). Per wave, per step t:
//   [prod flag cached >= t+1] -> issue x loads (hide under self-poll)
//   [self flags >= t]         -> issue h loads (slot (t-1)&3)
//   x-MFMAs, h-MFMAs          -> [WAR: cons flags >= t-3, cached]
//   finalize -> h stores slot t&3 -> wave vmcnt(0) fence -> flag = t+1.
// Flags are per (block,wave): 128 per layer. Self-WAR is implied by the
// self-poll (siblings >= t-1 done => slot t&3's old h(t-4) already read).
// ---------------------------------------------------------------------------
template <int NKX, bool XPLAIN, bool HASPROD, bool HASWAR>
__device__ void scan_layer(
    const unsigned* __restrict__ xb,      // XPLAIN: xs; else producer h buf
    unsigned* __restrict__ hbuf,          // own layer h buffer [4][16384] dw
    const int* __restrict__ fl_self, const int* __restrict__ fl_prod,
    const int* __restrict__ fl_cons, int* __restrict__ fl_mine,
    const unsigned short* __restrict__ wfrag, const float (&bias)[4][4],
    const int (&hstore)[4], int lane, int q, int laneoff) {
    float c_reg[4] = {0.f, 0.f, 0.f, 0.f};
    int prod_seen = 0, self_seen = 0, war_seen = 0;
    union Frag { i32x4 i4; f16x8 s; };

    for (int t = 0; t < T_; ++t) {
        // ---- producer gate (pre-satisfied in steady state), then x loads
        if (HASPROD && prod_seen < t + 1) {
            poll128(fl_prod, t + 1, lane);
            prod_seen = t + 1;
        }
        unsigned long long vx[NKX][2], vh[16][2];
        const unsigned* xsrc = XPLAIN ? (xb + (size_t)t * 4096 + laneoff)
                                      : (xb + (size_t)(t & 3) * 16384 + laneoff);
#pragma unroll
        for (int i = 0; i < NKX; ++i) {
            if (XPLAIN) {
                vx[i][0] = *(const unsigned long long*)(xsrc + i * 1024);
                vx[i][1] = *(const unsigned long long*)(xsrc + i * 1024 + 128);
            } else {
                vx[i][0] = loadc_u64(xsrc + i * 1024);
                vx[i][1] = loadc_u64(xsrc + i * 1024 + 128);
            }
        }
        // ---- self-loop gate: siblings published h(t-1)
        if (self_seen < t) {
            poll128(fl_self, t, lane);
            self_seen = t;
        }
        const unsigned* hs = hbuf + (size_t)((t + 3) & 3) * 16384 + laneoff;
#pragma unroll
        for (int j = 0; j < 16; ++j) {
            vh[j][0] = loadc_u64(hs + j * 1024);
            vh[j][1] = loadc_u64(hs + j * 1024 + 128);
        }

        f32x4 acc[4] = {{0.f,0.f,0.f,0.f},{0.f,0.f,0.f,0.f},
                        {0.f,0.f,0.f,0.f},{0.f,0.f,0.f,0.f}};
        // x-seg first (older loads), then h-seg (hides h-load latency)
#pragma unroll
        for (int i = 0; i < NKX; ++i) {
            Frag Bf, A0, A1, A2, A3;
            Bf.i4[0] = (int)(unsigned)vx[i][0];
            Bf.i4[1] = (int)(unsigned)(vx[i][0] >> 32);
            Bf.i4[2] = (int)(unsigned)vx[i][1];
            Bf.i4[3] = (int)(unsigned)(vx[i][1] >> 32);
            A0.i4 = *(const i32x4*)&wfrag[i * 2048 + lane * 8];
            A1.i4 = *(const i32x4*)&wfrag[i * 2048 + 512 + lane * 8];
            A2.i4 = *(const i32x4*)&wfrag[i * 2048 + 1024 + lane * 8];
            A3.i4 = *(const i32x4*)&wfrag[i * 2048 + 1536 + lane * 8];
            acc[0] = __builtin_amdgcn_mfma_f32_16x16x32_f16(A0.s, Bf.s, acc[0], 0, 0, 0);
            acc[1] = __builtin_amdgcn_mfma_f32_16x16x32_f16(A1.s, Bf.s, acc[1], 0, 0, 0);
            acc[2] = __builtin_amdgcn_mfma_f32_16x16x32_f16(A2.s, Bf.s, acc[2], 0, 0, 0);
            acc[3] = __builtin_amdgcn_mfma_f32_16x16x32_f16(A3.s, Bf.s, acc[3], 0, 0, 0);
        }
#pragma unroll
        for (int j = 0; j < 16; ++j) {
            Frag Bf, A0, A1, A2, A3;
            Bf.i4[0] = (int)(unsigned)vh[j][0];
            Bf.i4[1] = (int)(unsigned)(vh[j][0] >> 32);
            Bf.i4[2] = (int)(unsigned)vh[j][1];
            Bf.i4[3] = (int)(unsigned)(vh[j][1] >> 32);
            const int i = NKX + j;
            A0.i4 = *(const i32x4*)&wfrag[i * 2048 + lane * 8];
            A1.i4 = *(const i32x4*)&wfrag[i * 2048 + 512 + lane * 8];
            A2.i4 = *(const i32x4*)&wfrag[i * 2048 + 1024 + lane * 8];
            A3.i4 = *(const i32x4*)&wfrag[i * 2048 + 1536 + lane * 8];
            acc[0] = __builtin_amdgcn_mfma_f32_16x16x32_f16(A0.s, Bf.s, acc[0], 0, 0, 0);
            acc[1] = __builtin_amdgcn_mfma_f32_16x16x32_f16(A1.s, Bf.s, acc[1], 0, 0, 0);
            acc[2] = __builtin_amdgcn_mfma_f32_16x16x32_f16(A2.s, Bf.s, acc[2], 0, 0, 0);
            acc[3] = __builtin_amdgcn_mfma_f32_16x16x32_f16(A3.s, Bf.s, acc[3], 0, 0, 0);
        }

        // ---- cross-layer WAR: consumer finished step t-4 (flags >= t-3)
        if (HASWAR && t >= 4 && war_seen < t - 3) {
            poll128(fl_cons, t - 3, lane);
            war_seen = t - 3;
        }

        // ---- finalize in-register; pack + store h(t) into slot t&3
#pragma unroll
        for (int rg = 0; rg < 4; ++rg) {
            float a[4];
#pragma unroll
            for (int g = 0; g < 4; ++g) a[g] = bias[rg][g] + acc[rg][g];
            const float ig = sigmoid_(a[0]);
            const float fg = sigmoid_(a[1]);
            const float gg = tanh_(a[2]);
            const float og = sigmoid_(a[3]);
            c_reg[rg] = fg * c_reg[rg] + ig * gg;
            const float hv = og * tanh_(c_reg[rg]);
            const unsigned P0 = (unsigned)f2h(hv);
            const unsigned P1 = (unsigned)__shfl_xor((int)P0, 16, 64) & 0xFFFFu;
            const unsigned D  = P0 | (P1 << 16);
            const unsigned D2 = (unsigned)__shfl_xor((int)D, 32, 64);
            if (q == 0)
                storec_u64(hbuf + (size_t)(t & 3) * 16384 + hstore[rg],
                           ((unsigned long long)D2 << 32) | D);
        }
        // ---- wave-level publish: stores acked (vmcnt 0), then flag = t+1
        asm volatile("s_waitcnt vmcnt(0) lgkmcnt(0)" ::: "memory");
        if (lane == 0) storec_i(fl_mine, t + 1);
    }
}

// ---------------------------------------------------------------------------
// Persistent layer-pipelined LSTM. Block (layer=bid>>5, cb=bid&31) owns 64
// gate-rows (cols cb*16..+15 x gates i,f,g,o); wave w owns b-tile
// [16w,16w+16). No grid barrier: per-wave monotonic step flags (sc1).
// ---------------------------------------------------------------------------
__global__ void __launch_bounds__(256, 1) lstm_scan(
    const unsigned* __restrict__ xs, unsigned* __restrict__ hbf,
    int* __restrict__ fli, int* __restrict__ fcf,
    float* __restrict__ h1s, float* __restrict__ out,
    const float* __restrict__ Wih0, const float* __restrict__ Whh0,
    const float* __restrict__ bih0, const float* __restrict__ bhh0,
    const float* __restrict__ Wih1, const float* __restrict__ Whh1,
    const float* __restrict__ bih1, const float* __restrict__ bhh1,
    const float* __restrict__ Wih2, const float* __restrict__ Whh2,
    const float* __restrict__ bih2, const float* __restrict__ bhh2,
    const float* __restrict__ fcW1, const float* __restrict__ fcb1,
    const float* __restrict__ fcW2, const float* __restrict__ fcb2) {
    __shared__ unsigned short wfrag[32 * 2048];   // [kstep][rg 4][512], 128 KB
    __shared__ float redsc[4 * 64];               // FC-head reduction only

    const float* WihA[3] = {Wih0, Wih1, Wih2};
    const float* WhhA[3] = {Whh0, Whh1, Whh2};
    const float* bihA[3] = {bih0, bih1, bih2};
    const float* bhhA[3] = {bhh0, bhh1, bhh2};

    const int tid   = threadIdx.x;
    const int bid   = blockIdx.x;
    const int layer = bid >> 5;
    const int cb    = bid & 31;
    const int c0    = cb * 16;
    const int lane  = tid & 63;
    const int w     = __builtin_amdgcn_readfirstlane(tid >> 6);
    const int KX    = (layer == 0) ? F_ : H_;
    const int NK    = KX / 32 + 16;

    const float* wih = WihA[layer];
    const float* whh = WhhA[layer];

    // ---- Stage weights once: fp16 RN, A-frag order, 4 row-groups per kstep.
    for (int idx = tid; idx < NK * 2048; idx += 256) {
        const int i = idx >> 11, rem = idx & 2047;
        const int rg = rem >> 9, r2 = rem & 511;
        const int l = r2 >> 3, j = r2 & 7;
        const int m = l & 15;
        const int grow = (m & 3) * 512 + c0 + rg * 4 + (m >> 2);
        const int k = i * 32 + (l >> 4) * 8 + j;
        const float f = (k < KX) ? wih[(size_t)grow * KX + k]
                                 : whh[(size_t)grow * 512 + (k - KX)];
        wfrag[i * 2048 + rg * 512 + l * 8 + j] = f2h(f);
    }
    __syncthreads();

    // Finalize-role constants: lane owns (b = 16w + n, cols c0+rg*4+q).
    const int fb = w * 16 + (lane & 15);
    const int q  = lane >> 4;
    float bias[4][4];
#pragma unroll
    for (int rg = 0; rg < 4; ++rg)
#pragma unroll
        for (int g = 0; g < 4; ++g)
            bias[rg][g] = bihA[layer][g * 512 + c0 + rg * 4 + q] +
                          bhhA[layer][g * 512 + c0 + rg * 4 + q];

    int hstore[4];
#pragma unroll
    for (int rg = 0; rg < 4; ++rg) hstore[rg] = (cb * 4 + rg) * 128 + fb * 2;
    const int laneoff = q * 256 + fb * 2;

    // Buffers & flags. hbf: [3 layers][4 parities][16384 dw].
    unsigned* hbuf = hbf + (size_t)layer * 4 * 16384;
    const unsigned* xb =
        (layer == 0) ? xs : (hbf + (size_t)(layer - 1) * 4 * 16384);
    const int* fl_self = fli + layer * 128 * 32;
    const int* fl_prod = fli + (layer > 0 ? layer - 1 : 0) * 128 * 32;
    const int* fl_cons = fli + (layer < 2 ? layer + 1 : 2) * 128 * 32;
    int* fl_mine = fli + (layer * 128 + cb * 4 + w) * 32;

    if (layer == 0)
        scan_layer<4, true, false, true>(xb, hbuf, fl_self, fl_prod, fl_cons,
                                         fl_mine, wfrag, bias, hstore, lane, q,
                                         laneoff);
    else if (layer == 1)
        scan_layer<16, false, true, true>(xb, hbuf, fl_self, fl_prod, fl_cons,
                                          fl_mine, wfrag, bias, hstore, lane, q,
                                          laneoff);
    else
        scan_layer<16, false, true, false>(xb, hbuf, fl_self, fl_prod, fl_cons,
                                           fl_mine, wfrag, bias, hstore, lane,
                                           q, laneoff);

    // ---- FC head. h2 = layer-2 h(511) = slot 3, fp16 kquad layout.
    const unsigned* h2u = hbf + (size_t)2 * 4 * 16384 + (size_t)3 * 16384;
    const int fcb = tid & 63;
    if (bid < 64) {
        poll128(fli + 2 * 128 * 32, T_, lane);   // all layer-2 waves done
        float part = 0.0f;
        const float* wrow = fcW1 + (size_t)bid * H_ + w * 128;
#pragma unroll 8
        for (int k = 0; k < 128; ++k) {
            const int kk = w * 128 + k;
            const unsigned dv =
                loadc_u32(h2u + (kk >> 2) * 128 + fcb * 2 + ((kk >> 1) & 1));
            const float val = h2f((unsigned short)((dv >> ((kk & 1) * 16)) & 0xFFFFu));
            part = fmaf(wrow[k], val, part);
        }
        redsc[w * 64 + fcb] = part;
        __syncthreads();
        if (tid < 64) {
            float acc2 = fcb1[bid] + redsc[tid] + redsc[64 + tid] +
                         redsc[128 + tid] + redsc[192 + tid];
            storec_f(&h1s[bid * B_ + tid], fmaxf(acc2, 0.0f));
        }
        asm volatile("s_waitcnt vmcnt(0) lgkmcnt(0)" ::: "memory");
        __syncthreads();
        if (tid == 0) storec_i(&fcf[bid * 32], 1);
    }
    if (bid == 0) {
        if (tid < 64) {
            int g = 0;
            while (loadc_i(&fcf[tid * 32]) < 1 && ++g < SPIN_MAX)
                __builtin_amdgcn_s_sleep(1);
        }
        __syncthreads();
        if (tid < 64) {
            float acc2 = fcb2[0];
#pragma unroll
            for (int c = 0; c < 64; ++c)
                acc2 = fmaf(fcW2[c], loadc_f(&h1s[c * B_ + tid]), acc2);
            out[tid] = fmaxf(acc2, 0.0f);
        }
    }
}

// ---------------------------------------------------------------------------
extern "C" void kernel_launch(void* const* d_in, const int* in_sizes, int n_in,
                              void* d_out, int out_size, void* d_ws, size_t ws_size,
                              hipStream_t stream) {
    const float* in    = (const float*)d_in[0];
    const float* Wih0  = (const float*)d_in[1];
    const float* Whh0  = (const float*)d_in[2];
    const float* bih0  = (const float*)d_in[3];
    const float* bhh0  = (const float*)d_in[4];
    const float* Wih1  = (const float*)d_in[5];
    const float* Whh1  = (const float*)d_in[6];
    const float* bih1  = (const float*)d_in[7];
    const float* bhh1  = (const float*)d_in[8];
    const float* Wih2  = (const float*)d_in[9];
    const float* Whh2  = (const float*)d_in[10];
    const float* bih2  = (const float*)d_in[11];
    const float* bhh2  = (const float*)d_in[12];
    const float* fcW1  = (const float*)d_in[13];
    const float* fcb1  = (const float*)d_in[14];
    const float* fcW2  = (const float*)d_in[15];
    const float* fcb2  = (const float*)d_in[16];
    float* outp = (float*)d_out;

    unsigned* xs  = (unsigned*)d_ws;                   // [T][4096] dw     8 MB
    unsigned* hbf = xs + (size_t)T_ * 4096;            // [3][4][16384]  768 KB
    int* fli = (int*)(hbf + (size_t)3 * 4 * 16384);    // 3*128 flags x32  48 KB
    int* fcf = fli + 3 * 128 * 32;                     // 64 flags x32      8 KB
    float* h1s = (float*)(fcf + 64 * 32);              // [64][64]         16 KB

    // zero: hbf + fli + fcf + h1s (flags/state re-armed every graph replay)
    hipMemsetAsync(hbf, 0,
                   ((size_t)3 * 4 * 16384 + 3 * 128 * 32 + 64 * 32 + 64 * 64) *
                       sizeof(int),
                   stream);

    transpose_x<<<dim3(T_), dim3(256), 0, stream>>>(in, xs);

    void* args[] = {
        (void*)&xs, (void*)&hbf, (void*)&fli, (void*)&fcf, (void*)&h1s,
        (void*)&outp,
        (void*)&Wih0, (void*)&Whh0, (void*)&bih0, (void*)&bhh0,
        (void*)&Wih1, (void*)&Whh1, (void*)&bih1, (void*)&bhh1,
        (void*)&Wih2, (void*)&Whh2, (void*)&bih2, (void*)&bhh2,
        (void*)&fcW1, (void*)&fcb1, (void*)&fcW2, (void*)&fcb2};
    hipLaunchCooperativeKernel((void*)lstm_scan, dim3(NBLK), dim3(256), args, 0, stream);
}

// Round 7
// 2720.965 us; speedup vs baseline: 1.2112x; 1.2112x over previous
//
#include <hip/hip_runtime.h>
#include <hip/hip_fp16.h>
#include <math.h>

#define B_ 64
#define T_ 512
#define F_ 128
#define H_ 512
#define NBLK 96
#define SPIN_MAX (1 << 20)

typedef _Float16 f16x8 __attribute__((ext_vector_type(8)));
typedef float f32x4 __attribute__((ext_vector_type(4)));
typedef int   i32x4 __attribute__((ext_vector_type(4)));

__device__ __forceinline__ unsigned short f2h(float f) {
    return __half_as_ushort(__float2half(f));   // RN
}
__device__ __forceinline__ float h2f(unsigned short u) {
    return __half2float(__ushort_as_half(u));
}

// ---------------------------------------------------------------------------
// One-time input transform: input[b][t][f] -> fp16 kquad stream
// xs[t][kp2=f>>2][b][{dw0,dw1}]; dw_p = fp16(4kp2+2p) | fp16(4kp2+2p+1)<<16.
// ---------------------------------------------------------------------------
__global__ void transpose_x(const float* __restrict__ in, unsigned* __restrict__ xs) {
    const int t = blockIdx.x;
    for (int idx = threadIdx.x; idx < B_ * F_ / 4; idx += blockDim.x) {
        const int kp2 = idx >> 6;       // 0..31
        const int bb = idx & 63;
        const float* src = in + (size_t)bb * T_ * F_ + (size_t)t * F_ + 4 * kp2;
        const unsigned h0 = f2h(src[0]), h1 = f2h(src[1]);
        const unsigned h2 = f2h(src[2]), h3 = f2h(src[3]);
        const unsigned dw0 = h0 | (h1 << 16);
        const unsigned dw1 = h2 | (h3 << 16);
        *(unsigned long long*)(xs + (size_t)t * 4096 + (size_t)kp2 * 128 + bb * 2) =
            ((unsigned long long)dw1 << 32) | dw0;
    }
}

// Fast device transcendentals (proven R4).
__device__ __forceinline__ float sigmoid_(float x) {
    return __builtin_amdgcn_rcpf(1.0f + __expf(-x));
}
__device__ __forceinline__ float tanh_(float x) {
    return 1.0f - 2.0f * __builtin_amdgcn_rcpf(1.0f + __expf(2.0f * x));
}

// Device-coherent ops (relaxed agent-scope atomics -> sc1). Proven R0-R4.
__device__ __forceinline__ unsigned long long loadc_u64(const unsigned* p) {
    return __hip_atomic_load((const unsigned long long*)p, __ATOMIC_RELAXED,
                             __HIP_MEMORY_SCOPE_AGENT);
}
__device__ __forceinline__ unsigned loadc_u32(const unsigned* p) {
    return __hip_atomic_load(p, __ATOMIC_RELAXED, __HIP_MEMORY_SCOPE_AGENT);
}
__device__ __forceinline__ void storec_u64(unsigned* p, unsigned long long v) {
    __hip_atomic_store((unsigned long long*)p, v, __ATOMIC_RELAXED,
                       __HIP_MEMORY_SCOPE_AGENT);
}
__device__ __forceinline__ void storec_f(float* p, float v) {
    __hip_atomic_store(p, v, __ATOMIC_RELAXED, __HIP_MEMORY_SCOPE_AGENT);
}
__device__ __forceinline__ float loadc_f(const float* p) {
    return __hip_atomic_load(p, __ATOMIC_RELAXED, __HIP_MEMORY_SCOPE_AGENT);
}
__device__ __forceinline__ int loadc_i(const int* p) {
    return __hip_atomic_load(p, __ATOMIC_RELAXED, __HIP_MEMORY_SCOPE_AGENT);
}
__device__ __forceinline__ void storec_i(int* p, int v) {
    __hip_atomic_store(p, v, __ATOMIC_RELAXED, __HIP_MEMORY_SCOPE_AGENT);
}

// ---------------------------------------------------------------------------
// Split flat barrier (96 slots). arrive = fence own stores + publish;
// wait = 96 threads poll one slot each. x-prefetch for the NEXT step is
// issued between arrive and wait so its LLC latency hides under the poll.
// ---------------------------------------------------------------------------
__device__ __forceinline__ void gbar_arrive(int* __restrict__ slots, int bid,
                                            int tid, int e) {
    asm volatile("s_waitcnt vmcnt(0) lgkmcnt(0)" ::: "memory");
    __syncthreads();
    if (tid == 0) storec_i(&slots[bid * 16], e);
}
__device__ __forceinline__ void gbar_wait(const int* __restrict__ slots, int tid,
                                          int e) {
    if (tid < NBLK) {
        int g = 0;
        while (loadc_i(&slots[tid * 16]) < e && ++g < SPIN_MAX)
            __builtin_amdgcn_s_sleep(1);
    }
    __syncthreads();
}

// ---------------------------------------------------------------------------
// Per-layer scan with lag-2 layer pipeline (layer l runs step t at epoch
// t + 2l) and 4-parity h buffers. Per epoch:
//   [poll e]: sync -> issue 32 h-loads -> x-MFMAs (prefetched regs) ->
//   h-MFMAs -> finalize -> h-store slot t&3 ->
//   [arrive e+1] -> prefetch x(t+1) (safe: written at epoch e-1) -> [poll e+1]
// WAR windows (4 parities, lag 2): self overwrite t+4 = read epoch +3;
// producer overwrite of prefetched slot = issue epoch +3. Both safe.
// ---------------------------------------------------------------------------
template <int NKX, bool XPLAIN>
__device__ void scan_layer(const unsigned* __restrict__ xb,
                           unsigned* __restrict__ hbuf,   // [4][16384] dw
                           int* __restrict__ slots, int bid, int tid,
                           const unsigned short* __restrict__ wfrag,
                           const float (&bias)[4][4], const int (&hstore)[4],
                           int lane, int q, int laneoff, int twol) {
    float c_reg[4] = {0.f, 0.f, 0.f, 0.f};
    unsigned long long vx[NKX][2];
    union Frag { i32x4 i4; f16x8 s; };

    auto pref = [&](int tt) {
        if (tt < 0 || tt >= T_) return;
        const unsigned* xsrc = XPLAIN ? (xb + (size_t)tt * 4096 + laneoff)
                                      : (xb + (size_t)(tt & 3) * 16384 + laneoff);
#pragma unroll
        for (int i = 0; i < NKX; ++i) {
            if (XPLAIN) {
                vx[i][0] = *(const unsigned long long*)(xsrc + i * 1024);
                vx[i][1] = *(const unsigned long long*)(xsrc + i * 1024 + 128);
            } else {
                vx[i][0] = loadc_u64(xsrc + i * 1024);
                vx[i][1] = loadc_u64(xsrc + i * 1024 + 128);
            }
        }
    };

    if (XPLAIN) pref(0);   // layer 0: xs is static, prefetch t=0 pre-loop

    for (int s = 0; s < T_ + 4; ++s) {
        const int t = s - twol;
        if (t >= 0 && t < T_) {
            // ---- issue all 32 h-loads (depth 32), slot (t-1)&3
            unsigned long long vh[16][2];
            const unsigned* hs = hbuf + (size_t)((t + 3) & 3) * 16384 + laneoff;
#pragma unroll
            for (int j = 0; j < 16; ++j) {
                vh[j][0] = loadc_u64(hs + j * 1024);
                vh[j][1] = loadc_u64(hs + j * 1024 + 128);
            }

            f32x4 acc[4] = {{0.f,0.f,0.f,0.f},{0.f,0.f,0.f,0.f},
                            {0.f,0.f,0.f,0.f},{0.f,0.f,0.f,0.f}};
            // ---- x-MFMAs first: vx already resident (prefetched last epoch)
#pragma unroll
            for (int i = 0; i < NKX; ++i) {
                Frag Bf, A0, A1, A2, A3;
                Bf.i4[0] = (int)(unsigned)vx[i][0];
                Bf.i4[1] = (int)(unsigned)(vx[i][0] >> 32);
                Bf.i4[2] = (int)(unsigned)vx[i][1];
                Bf.i4[3] = (int)(unsigned)(vx[i][1] >> 32);
                A0.i4 = *(const i32x4*)&wfrag[i * 2048 + lane * 8];
                A1.i4 = *(const i32x4*)&wfrag[i * 2048 + 512 + lane * 8];
                A2.i4 = *(const i32x4*)&wfrag[i * 2048 + 1024 + lane * 8];
                A3.i4 = *(const i32x4*)&wfrag[i * 2048 + 1536 + lane * 8];
                acc[0] = __builtin_amdgcn_mfma_f32_16x16x32_f16(A0.s, Bf.s, acc[0], 0, 0, 0);
                acc[1] = __builtin_amdgcn_mfma_f32_16x16x32_f16(A1.s, Bf.s, acc[1], 0, 0, 0);
                acc[2] = __builtin_amdgcn_mfma_f32_16x16x32_f16(A2.s, Bf.s, acc[2], 0, 0, 0);
                acc[3] = __builtin_amdgcn_mfma_f32_16x16x32_f16(A3.s, Bf.s, acc[3], 0, 0, 0);
            }
            // ---- h-MFMAs
#pragma unroll
            for (int j = 0; j < 16; ++j) {
                Frag Bf, A0, A1, A2, A3;
                Bf.i4[0] = (int)(unsigned)vh[j][0];
                Bf.i4[1] = (int)(unsigned)(vh[j][0] >> 32);
                Bf.i4[2] = (int)(unsigned)vh[j][1];
                Bf.i4[3] = (int)(unsigned)(vh[j][1] >> 32);
                const int i = NKX + j;
                A0.i4 = *(const i32x4*)&wfrag[i * 2048 + lane * 8];
                A1.i4 = *(const i32x4*)&wfrag[i * 2048 + 512 + lane * 8];
                A2.i4 = *(const i32x4*)&wfrag[i * 2048 + 1024 + lane * 8];
                A3.i4 = *(const i32x4*)&wfrag[i * 2048 + 1536 + lane * 8];
                acc[0] = __builtin_amdgcn_mfma_f32_16x16x32_f16(A0.s, Bf.s, acc[0], 0, 0, 0);
                acc[1] = __builtin_amdgcn_mfma_f32_16x16x32_f16(A1.s, Bf.s, acc[1], 0, 0, 0);
                acc[2] = __builtin_amdgcn_mfma_f32_16x16x32_f16(A2.s, Bf.s, acc[2], 0, 0, 0);
                acc[3] = __builtin_amdgcn_mfma_f32_16x16x32_f16(A3.s, Bf.s, acc[3], 0, 0, 0);
            }

            // ---- finalize in-register; pack + store h(t) into slot t&3
#pragma unroll
            for (int rg = 0; rg < 4; ++rg) {
                float a[4];
#pragma unroll
                for (int g = 0; g < 4; ++g) a[g] = bias[rg][g] + acc[rg][g];
                const float ig = sigmoid_(a[0]);
                const float fg = sigmoid_(a[1]);
                const float gg = tanh_(a[2]);
                const float og = sigmoid_(a[3]);
                c_reg[rg] = fg * c_reg[rg] + ig * gg;
                const float hv = og * tanh_(c_reg[rg]);
                const unsigned P0 = (unsigned)f2h(hv);
                const unsigned P1 = (unsigned)__shfl_xor((int)P0, 16, 64) & 0xFFFFu;
                const unsigned D  = P0 | (P1 << 16);
                const unsigned D2 = (unsigned)__shfl_xor((int)D, 32, 64);
                if (q == 0)
                    storec_u64(hbuf + (size_t)(t & 3) * 16384 + hstore[rg],
                               ((unsigned long long)D2 << 32) | D);
            }
        }
        gbar_arrive(slots, bid, tid, s + 1);
        __builtin_amdgcn_sched_barrier(0);
        pref(s + 1 - twol);                 // hide under the poll below
        __builtin_amdgcn_sched_barrier(0);
        gbar_wait(slots, tid, s + 1);
    }
}

// ---------------------------------------------------------------------------
// Persistent layer-pipelined LSTM. Block (layer=bid>>5, cb=bid&31) owns 64
// gate-rows (cols cb*16..+15 x gates i,f,g,o); wave w owns b-tile
// [16w,16w+16). Lag-2 layer pipeline, 4-parity h buffers, split barrier
// with cross-barrier x prefetch.
// ---------------------------------------------------------------------------
__global__ void __launch_bounds__(256, 1) lstm_scan(
    const unsigned* __restrict__ xs, unsigned* __restrict__ hbf,
    float* __restrict__ h1s, float* __restrict__ out,
    int* __restrict__ bar_slots,
    const float* __restrict__ Wih0, const float* __restrict__ Whh0,
    const float* __restrict__ bih0, const float* __restrict__ bhh0,
    const float* __restrict__ Wih1, const float* __restrict__ Whh1,
    const float* __restrict__ bih1, const float* __restrict__ bhh1,
    const float* __restrict__ Wih2, const float* __restrict__ Whh2,
    const float* __restrict__ bih2, const float* __restrict__ bhh2,
    const float* __restrict__ fcW1, const float* __restrict__ fcb1,
    const float* __restrict__ fcW2, const float* __restrict__ fcb2) {
    __shared__ unsigned short wfrag[32 * 2048];   // [kstep][rg 4][512], 128 KB
    __shared__ float redsc[4 * 64];               // FC-head reduction only

    const float* WihA[3] = {Wih0, Wih1, Wih2};
    const float* WhhA[3] = {Whh0, Whh1, Whh2};
    const float* bihA[3] = {bih0, bih1, bih2};
    const float* bhhA[3] = {bhh0, bhh1, bhh2};

    const int tid   = threadIdx.x;
    const int bid   = blockIdx.x;
    const int layer = bid >> 5;
    const int cb    = bid & 31;
    const int c0    = cb * 16;
    const int lane  = tid & 63;
    const int w     = __builtin_amdgcn_readfirstlane(tid >> 6);
    const int KX    = (layer == 0) ? F_ : H_;
    const int NK    = KX / 32 + 16;

    const float* wih = WihA[layer];
    const float* whh = WhhA[layer];

    // ---- Stage weights once: fp16 RN, A-frag order, 4 row-groups per kstep.
    for (int idx = tid; idx < NK * 2048; idx += 256) {
        const int i = idx >> 11, rem = idx & 2047;
        const int rg = rem >> 9, r2 = rem & 511;
        const int l = r2 >> 3, j = r2 & 7;
        const int m = l & 15;
        const int grow = (m & 3) * 512 + c0 + rg * 4 + (m >> 2);
        const int k = i * 32 + (l >> 4) * 8 + j;
        const float f = (k < KX) ? wih[(size_t)grow * KX + k]
                                 : whh[(size_t)grow * 512 + (k - KX)];
        wfrag[i * 2048 + rg * 512 + l * 8 + j] = f2h(f);
    }
    __syncthreads();

    // Finalize-role constants: lane owns (b = 16w + n, cols c0+rg*4+q).
    const int fb = w * 16 + (lane & 15);
    const int q  = lane >> 4;
    float bias[4][4];
#pragma unroll
    for (int rg = 0; rg < 4; ++rg)
#pragma unroll
        for (int g = 0; g < 4; ++g)
            bias[rg][g] = bihA[layer][g * 512 + c0 + rg * 4 + q] +
                          bhhA[layer][g * 512 + c0 + rg * 4 + q];

    int hstore[4];
#pragma unroll
    for (int rg = 0; rg < 4; ++rg) hstore[rg] = (cb * 4 + rg) * 128 + fb * 2;
    const int laneoff = q * 256 + fb * 2;

    // Buffers. hbf: [3 layers][4 parities][16384 dw].
    unsigned* hbuf = hbf + (size_t)layer * 4 * 16384;
    const unsigned* xb =
        (layer == 0) ? xs : (hbf + (size_t)(layer - 1) * 4 * 16384);

    if (layer == 0)
        scan_layer<4, true>(xb, hbuf, bar_slots, bid, tid, wfrag, bias, hstore,
                            lane, q, laneoff, 0);
    else if (layer == 1)
        scan_layer<16, false>(xb, hbuf, bar_slots, bid, tid, wfrag, bias,
                              hstore, lane, q, laneoff, 2);
    else
        scan_layer<16, false>(xb, hbuf, bar_slots, bid, tid, wfrag, bias,
                              hstore, lane, q, laneoff, 4);

    // ---- FC head. h2 = layer-2 h(511) = slot 511&3 = 3, fp16 kquad layout.
    const unsigned* h2u = hbf + (size_t)2 * 4 * 16384 + (size_t)3 * 16384;
    const int fcb = tid & 63;
    if (bid < 64) {
        float part = 0.0f;
        const float* wrow = fcW1 + (size_t)bid * H_ + w * 128;
#pragma unroll 8
        for (int k = 0; k < 128; ++k) {
            const int kk = w * 128 + k;
            const unsigned dv =
                loadc_u32(h2u + (kk >> 2) * 128 + fcb * 2 + ((kk >> 1) & 1));
            const float val = h2f((unsigned short)((dv >> ((kk & 1) * 16)) & 0xFFFFu));
            part = fmaf(wrow[k], val, part);
        }
        redsc[w * 64 + fcb] = part;
        __syncthreads();
        if (tid < 64) {
            float acc2 = fcb1[bid] + redsc[tid] + redsc[64 + tid] +
                         redsc[128 + tid] + redsc[192 + tid];
            storec_f(&h1s[bid * B_ + tid], fmaxf(acc2, 0.0f));
        }
    }
    gbar_arrive(bar_slots, bid, tid, T_ + 5);
    gbar_wait(bar_slots, tid, T_ + 5);
    if (bid == 0 && tid < 64) {
        float acc2 = fcb2[0];
#pragma unroll
        for (int c = 0; c < 64; ++c)
            acc2 = fmaf(fcW2[c], loadc_f(&h1s[c * B_ + tid]), acc2);
        out[tid] = fmaxf(acc2, 0.0f);
    }
}

// ---------------------------------------------------------------------------
extern "C" void kernel_launch(void* const* d_in, const int* in_sizes, int n_in,
                              void* d_out, int out_size, void* d_ws, size_t ws_size,
                              hipStream_t stream) {
    const float* in    = (const float*)d_in[0];
    const float* Wih0  = (const float*)d_in[1];
    const float* Whh0  = (const float*)d_in[2];
    const float* bih0  = (const float*)d_in[3];
    const float* bhh0  = (const float*)d_in[4];
    const float* Wih1  = (const float*)d_in[5];
    const float* Whh1  = (const float*)d_in[6];
    const float* bih1  = (const float*)d_in[7];
    const float* bhh1  = (const float*)d_in[8];
    const float* Wih2  = (const float*)d_in[9];
    const float* Whh2  = (const float*)d_in[10];
    const float* bih2  = (const float*)d_in[11];
    const float* bhh2  = (const float*)d_in[12];
    const float* fcW1  = (const float*)d_in[13];
    const float* fcb1  = (const float*)d_in[14];
    const float* fcW2  = (const float*)d_in[15];
    const float* fcb2  = (const float*)d_in[16];
    float* outp = (float*)d_out;

    unsigned* xs  = (unsigned*)d_ws;                   // [T][4096] dw     8 MB
    unsigned* hbf = xs + (size_t)T_ * 4096;            // [3][4][16384]  3 MB
    float* h1s = (float*)(hbf + (size_t)3 * 4 * 16384);// [64][64]       16 KB
    int* bar_slots = (int*)(h1s + 64 * 64);            // NBLK*16 ints

    hipMemsetAsync(hbf, 0,
                   ((size_t)3 * 4 * 16384 + 64 * 64 + NBLK * 16 + 16) * sizeof(int),
                   stream);

    transpose_x<<<dim3(T_), dim3(256), 0, stream>>>(in, xs);

    void* args[] = {
        (void*)&xs, (void*)&hbf, (void*)&h1s, (void*)&outp, (void*)&bar_slots,
        (void*)&Wih0, (void*)&Whh0, (void*)&bih0, (void*)&bhh0,
        (void*)&Wih1, (void*)&Whh1, (void*)&bih1, (void*)&bhh1,
        (void*)&Wih2, (void*)&Whh2, (void*)&bih2, (void*)&bhh2,
        (void*)&fcW1, (void*)&fcb1, (void*)&fcW2, (void*)&fcb2};
    hipLaunchCooperativeKernel((void*)lstm_scan, dim3(NBLK), dim3(256), args, 0, stream);
}